// Round 1
// baseline (459.062 us; speedup 1.0000x reference)
//
#include <hip/hip_runtime.h>
#include <hip/hip_bf16.h>

// CalcSpixelFeats: scatter pixel features into superpixel bins with 3x3
// neighbor association weights, then normalize. B=4, C=32, P=H*W, K=nw*nh.
//
// Strategy: per-block LDS accumulator [K][C+1] (stride 33 -> bank spread for
// random target bins), ds_add_f32 atomics, partial-sum flush to d_ws
// (no global atomics), then a reduce+normalize+transpose kernel.

#define CCH 32          // channels (C) — fixed by problem (in_sizes[0]/in_sizes[2])
#define TPB 256
#define ACC_STRIDE 33   // C + 1 (wsum in col 32); 33 mod 32 = 1 -> bank=(t+c)%32

__global__ __launch_bounds__(TPB) void spx_accum_kernel(
    const float* __restrict__ pf,      // [B][C][P]
    const float* __restrict__ assoc,   // [B][9][P]
    const int*   __restrict__ idxmap,  // [B][P]
    const int*   __restrict__ nw_p,
    const int*   __restrict__ nh_p,
    float* __restrict__ part_f,        // [B*G][K][C]
    float* __restrict__ part_w,        // [B*G][K]
    int P, int K, int G, int ppb)
{
    extern __shared__ float acc[];     // K * ACC_STRIDE
    const int b   = blockIdx.x / G;
    const int g   = blockIdx.x % G;
    const int tid = threadIdx.x;
    const int nw  = nw_p[0];
    const int nh  = nh_p[0];

    const int n_acc = K * ACC_STRIDE;
    for (int i = tid; i < n_acc; i += TPB) acc[i] = 0.0f;
    __syncthreads();

    const float* pf_b = pf    + (size_t)b * CCH * P;
    const float* as_b = assoc + (size_t)b * 9 * P;
    const int*   ix_b = idxmap + (size_t)b * P;

    const int p0   = g * ppb;
    const int pend = (p0 + ppb < P) ? (p0 + ppb) : P;

    for (int p = p0 + tid; p < pend; p += TPB) {
        const int idx = ix_b[p];
        const int iy  = idx / nw;
        const int ix  = idx - iy * nw;

        float w[9];
        int   base[9];   // LDS float-index of target bin row, or -1 if invalid
#pragma unroll
        for (int j = 0; j < 9; ++j) {
            const int dy = j / 3 - 1;
            const int dx = j % 3 - 1;
            const int ty = iy + dy;
            const int tx = ix + dx;
            const bool valid = (tx >= 0) & (tx < nw) & (ty >= 0) & (ty < nh);
            const float wj = as_b[(size_t)j * P + p];
            w[j]    = valid ? wj : 0.0f;
            base[j] = valid ? (ty * nw + tx) * ACC_STRIDE : -1;
        }

        // wsum
#pragma unroll
        for (int j = 0; j < 9; ++j) {
            if (base[j] >= 0) atomicAdd(&acc[base[j] + CCH], w[j]);
        }

        // weighted features; c unrolled so ds ops get immediate offsets
#pragma unroll 8
        for (int c = 0; c < CCH; ++c) {
            const float f = pf_b[(size_t)c * P + p];
#pragma unroll
            for (int j = 0; j < 9; ++j) {
                if (base[j] >= 0) atomicAdd(&acc[base[j] + c], w[j] * f);
            }
        }
    }
    __syncthreads();

    // Flush partials, fully coalesced. fsum part: [K][C] contiguous.
    float* pfo = part_f + (size_t)blockIdx.x * K * CCH;
    for (int i = tid; i < K * CCH; i += TPB) {
        const int t = i >> 5;        // /32
        const int c = i & 31;        // %32
        pfo[i] = acc[t * ACC_STRIDE + c];
    }
    float* pwo = part_w + (size_t)blockIdx.x * K;
    for (int i = tid; i < K; i += TPB) pwo[i] = acc[i * ACC_STRIDE + CCH];
}

__global__ __launch_bounds__(TPB) void spx_finalize_kernel(
    const float* __restrict__ part_f,  // [B*G][K][C]
    const float* __restrict__ part_w,  // [B*G][K]
    float* __restrict__ out,           // [B][C][K]
    int K, int G, int total)           // total = B*K*C
{
    const int gid = blockIdx.x * TPB + threadIdx.x;
    if (gid >= total) return;
    // gid -> (b, t, c), c fastest => coalesced partial reads
    const int c = gid & (CCH - 1);
    const int t = (gid / CCH) % K;
    const int b = gid / (CCH * K);

    float fs = 0.0f, ws = 0.0f;
    for (int g = 0; g < G; ++g) {
        const size_t row = (size_t)(b * G + g) * K + t;
        fs += part_f[row * CCH + c];
        ws += part_w[row];
    }
    const float r = (ws > 1e-16f) ? (fs / ws) : 0.0f;
    out[((size_t)b * CCH + c) * K + t] = r;
}

extern "C" void kernel_launch(void* const* d_in, const int* in_sizes, int n_in,
                              void* d_out, int out_size, void* d_ws, size_t ws_size,
                              hipStream_t stream) {
    const float* pf     = (const float*)d_in[0];
    const float* assoc  = (const float*)d_in[1];
    const int*   idxmap = (const int*)d_in[2];
    const int*   nw_p   = (const int*)d_in[3];
    const int*   nh_p   = (const int*)d_in[4];
    float* out = (float*)d_out;

    const int BP = in_sizes[2];        // B*P = 262144
    const int B  = 4;                  // fixed by reference setup
    const int P  = BP / B;             // 65536
    const int K  = out_size / (B * CCH); // 256

    // G partial blocks per batch; shrink if workspace is small.
    int G = 64;
    while (G > 1 &&
           (size_t)B * G * K * (CCH + 1) * sizeof(float) > ws_size) {
        G >>= 1;
    }
    const int ppb = (P + G - 1) / G;

    float* part_f = (float*)d_ws;                       // [B*G][K][C]
    float* part_w = part_f + (size_t)B * G * K * CCH;   // [B*G][K]

    const int    nblocks1 = B * G;
    const size_t shmem    = (size_t)K * ACC_STRIDE * sizeof(float);
    spx_accum_kernel<<<nblocks1, TPB, shmem, stream>>>(
        pf, assoc, idxmap, nw_p, nh_p, part_f, part_w, P, K, G, ppb);

    const int total    = B * K * CCH;
    const int nblocks2 = (total + TPB - 1) / TPB;
    spx_finalize_kernel<<<nblocks2, TPB, 0, stream>>>(
        part_f, part_w, out, K, G, total);
}

// Round 2
// 442.730 us; speedup vs baseline: 1.0369x; 1.0369x over previous
//
#include <hip/hip_runtime.h>
#include <hip/hip_bf16.h>

// CalcSpixelFeats: scatter pixel features into superpixel bins with 3x3
// neighbor association weights, then normalize. B=4, C=32, P=H*W, K=nw*nh.
//
// R2: occupancy fix. R1 ran 1 wave/SIMD (256 blocks x 256 thr) and was pure
// exposed-latency (VALUBusy 1%, occupancy 12%, 640 cy/instr). Now:
//   accum: 256 blocks x 1024 thr = 16 waves/CU, 1 pixel/thread, full c-unroll
//          so all ~42 global loads issue before a single vmcnt wait.
//   finalize: block per (b,t) = 1024 blocks, LDS tree-reduce over G partials.

#define CCH 32          // channels (C) — fixed by problem
#define TPB 1024        // accum block: 16 waves
#define ACC_STRIDE 33   // C + 1 (wsum in col 32); 33 mod 32 = 1 -> bank spread

__global__ __launch_bounds__(TPB) void spx_accum_kernel(
    const float* __restrict__ pf,      // [B][C][P]
    const float* __restrict__ assoc,   // [B][9][P]
    const int*   __restrict__ idxmap,  // [B][P]
    const int*   __restrict__ nw_p,
    const int*   __restrict__ nh_p,
    float* __restrict__ part_f,        // [B*G][K][C]
    float* __restrict__ part_w,        // [B*G][K]
    int P, int K, int G, int ppb)
{
    extern __shared__ float acc[];     // K * ACC_STRIDE
    const int b   = blockIdx.x / G;
    const int g   = blockIdx.x % G;
    const int tid = threadIdx.x;
    const int nw  = nw_p[0];
    const int nh  = nh_p[0];

    const int n_acc = K * ACC_STRIDE;
    for (int i = tid; i < n_acc; i += TPB) acc[i] = 0.0f;
    __syncthreads();

    const float* pf_b = pf    + (size_t)b * CCH * P;
    const float* as_b = assoc + (size_t)b * 9 * P;
    const int*   ix_b = idxmap + (size_t)b * P;

    const int p0   = g * ppb;
    const int pend = (p0 + ppb < P) ? (p0 + ppb) : P;

    for (int p = p0 + tid; p < pend; p += TPB) {
        const int idx = ix_b[p];
        const int iy  = idx / nw;
        const int ix  = idx - iy * nw;

        // issue all 9 assoc loads + all 32 feature loads up front (MLP)
        float w[9];
        int   base[9];
#pragma unroll
        for (int j = 0; j < 9; ++j) {
            const int dy = j / 3 - 1;
            const int dx = j % 3 - 1;
            const int ty = iy + dy;
            const int tx = ix + dx;
            const bool valid = (tx >= 0) & (tx < nw) & (ty >= 0) & (ty < nh);
            const float wj = as_b[(size_t)j * P + p];
            w[j]    = valid ? wj : 0.0f;
            base[j] = valid ? (ty * nw + tx) * ACC_STRIDE : -1;
        }

        float f[CCH];
#pragma unroll
        for (int c = 0; c < CCH; ++c) f[c] = pf_b[(size_t)c * P + p];

#pragma unroll
        for (int j = 0; j < 9; ++j) {
            if (base[j] >= 0) {
                atomicAdd(&acc[base[j] + CCH], w[j]);
#pragma unroll
                for (int c = 0; c < CCH; ++c) {
                    atomicAdd(&acc[base[j] + c], w[j] * f[c]);
                }
            }
        }
    }
    __syncthreads();

    // Flush partials, fully coalesced. fsum part: [K][C] contiguous.
    float* pfo = part_f + (size_t)blockIdx.x * K * CCH;
    for (int i = tid; i < K * CCH; i += TPB) {
        const int t = i >> 5;        // /32
        const int c = i & 31;        // %32
        pfo[i] = acc[t * ACC_STRIDE + c];
    }
    float* pwo = part_w + (size_t)blockIdx.x * K;
    for (int i = tid; i < K; i += TPB) pwo[i] = acc[i * ACC_STRIDE + CCH];
}

// One block per (b, t): 256 threads = 8 g-lanes x 32 channels.
__global__ __launch_bounds__(256) void spx_finalize_kernel(
    const float* __restrict__ part_f,  // [B*G][K][C]
    const float* __restrict__ part_w,  // [B*G][K]
    float* __restrict__ out,           // [B][C][K]
    int K, int G)
{
    const int b   = blockIdx.x / K;
    const int t   = blockIdx.x % K;
    const int tid = threadIdx.x;
    const int c   = tid & 31;
    const int g0  = tid >> 5;          // 0..7

    float fs = 0.0f, ws = 0.0f;
    for (int g = g0; g < G; g += 8) {
        const size_t row = (size_t)(b * G + g) * K + t;
        fs += part_f[row * CCH + c];
        ws += part_w[row];             // broadcast across the 32 c-lanes
    }

    __shared__ float redf[8][ACC_STRIDE];
    redf[g0][c] = fs;
    if (c == 0) redf[g0][CCH] = ws;
    __syncthreads();

    if (tid < CCH) {
        float F = 0.0f, W = 0.0f;
#pragma unroll
        for (int r = 0; r < 8; ++r) {
            F += redf[r][tid];
            W += redf[r][CCH];
        }
        const float res = (W > 1e-16f) ? (F / W) : 0.0f;
        out[((size_t)b * CCH + tid) * K + t] = res;
    }
}

extern "C" void kernel_launch(void* const* d_in, const int* in_sizes, int n_in,
                              void* d_out, int out_size, void* d_ws, size_t ws_size,
                              hipStream_t stream) {
    const float* pf     = (const float*)d_in[0];
    const float* assoc  = (const float*)d_in[1];
    const int*   idxmap = (const int*)d_in[2];
    const int*   nw_p   = (const int*)d_in[3];
    const int*   nh_p   = (const int*)d_in[4];
    float* out = (float*)d_out;

    const int BP = in_sizes[2];          // B*P = 262144
    const int B  = 4;                    // fixed by reference setup
    const int P  = BP / B;               // 65536
    const int K  = out_size / (B * CCH); // 256

    int G = 64;
    while (G > 1 &&
           (size_t)B * G * K * (CCH + 1) * sizeof(float) > ws_size) {
        G >>= 1;
    }
    const int ppb = (P + G - 1) / G;

    float* part_f = (float*)d_ws;                       // [B*G][K][C]
    float* part_w = part_f + (size_t)B * G * K * CCH;   // [B*G][K]

    const int    nblocks1 = B * G;
    const size_t shmem    = (size_t)K * ACC_STRIDE * sizeof(float);
    spx_accum_kernel<<<nblocks1, TPB, shmem, stream>>>(
        pf, assoc, idxmap, nw_p, nh_p, part_f, part_w, P, K, G, ppb);

    const int nblocks2 = B * K;
    spx_finalize_kernel<<<nblocks2, 256, 0, stream>>>(
        part_f, part_w, out, K, G);
}